// Round 3
// baseline (787.284 us; speedup 1.0000x reference)
//
#include <hip/hip_runtime.h>
#include <hip/hip_bf16.h>

typedef __hip_bfloat16 bf16;
typedef __attribute__((ext_vector_type(8))) short short8;
typedef __attribute__((ext_vector_type(4))) float floatx4;

#define DM   768
#define NH   12
#define DH   64
#define DFF  3072
#define TS   4096
#define NB   2
#define MTOK (NB * TS)
#define EPS  1e-5f
#define NEG  -30000.0f

__device__ __forceinline__ float b2f(bf16 v)  { return __bfloat162float(v); }
__device__ __forceinline__ bf16  f2b(float v) { return __float2bfloat16(v); }
__device__ __forceinline__ short sbf(float x) { bf16 b = __float2bfloat16(x); return *(short*)&b; }
__device__ __forceinline__ float ldf(const float* p) { return *p; }
__device__ __forceinline__ float ldf(const bf16*  p) { return b2f(*p); }
__device__ __forceinline__ void stf(float* p, float v) { *p = v; }
__device__ __forceinline__ void stf(bf16*  p, float v) { *p = f2b(v); }
// pack two floats into one dword of 2x bf16 (lo in bits 0-15)
__device__ __forceinline__ unsigned pk2(float lo, float hi) {
    return ((unsigned)(unsigned short)sbf(hi) << 16) | (unsigned short)sbf(lo);
}

// Full-rate VALU cross-lane via DPP (NOT ds_bpermute — v3 lesson).
// Reduction over the 16 contiguous lanes of a DPP row:
//   quad_perm xor1 (0xB1), quad_perm xor2 (0x4E),
//   row_half_mirror (0x141, i->i^7 within 8), row_mirror (0x140, i->i^15).
// After each round values are uniform on the combined group, so the mirrors
// are equivalent to xor4 / xor8 for reduction purposes.
template <int CTRL>
__device__ __forceinline__ float dppf(float x) {
    return __int_as_float(__builtin_amdgcn_update_dpp(
        0, __float_as_int(x), CTRL, 0xF, 0xF, true));
}
__device__ __forceinline__ float rowmax16(float m) {
    m = fmaxf(m, dppf<0xB1>(m));
    m = fmaxf(m, dppf<0x4E>(m));
    m = fmaxf(m, dppf<0x141>(m));
    m = fmaxf(m, dppf<0x140>(m));
    return m;
}
__device__ __forceinline__ float rowsum16(float s) {
    s += dppf<0xB1>(s);
    s += dppf<0x4E>(s);
    s += dppf<0x141>(s);
    s += dppf<0x140>(s);
    return s;
}

// ---------------------------------------------------------------------------
// MFMA GEMM (PROVEN round 6) — unchanged.
// ---------------------------------------------------------------------------
template <int RELU, typename TA>
__global__ __launch_bounds__(256)
void gemm_mfma(const TA* __restrict__ A, int lda, const bf16* __restrict__ Wt,
               const float* __restrict__ bias, bf16* __restrict__ C, int ldc,
               int N, int K)
{
    constexpr int LDT = 40;
    __shared__ __align__(16) short As[128 * LDT];
    __shared__ __align__(16) short Bs[128 * LDT];

    const int tid  = threadIdx.x;
    const int wave = tid >> 6, lane = tid & 63;
    const int wx = wave & 1, wy = wave >> 1;
    const int quad = lane >> 4, fn = lane & 15;
    const int bm = blockIdx.y * 128, bn = blockIdx.x * 128;

    floatx4 acc[4][4] = {};
    const int sr = tid >> 2, sc8 = (tid & 3) * 8;

    for (int kk = 0; kk < K; kk += 32) {
        __syncthreads();
        if constexpr (sizeof(TA) == 2) {
            *(short8*)&As[sr * LDT + sc8] =
                *(const short8*)&A[(size_t)(bm + sr) * lda + kk + sc8];
            *(short8*)&As[(sr + 64) * LDT + sc8] =
                *(const short8*)&A[(size_t)(bm + sr + 64) * lda + kk + sc8];
        } else {
            const float* p0 = (const float*)A + (size_t)(bm + sr) * lda + kk + sc8;
            const float* p1 = (const float*)A + (size_t)(bm + sr + 64) * lda + kk + sc8;
            float4 a0 = *(const float4*)p0, a1 = *(const float4*)(p0 + 4);
            float4 c0 = *(const float4*)p1, c1 = *(const float4*)(p1 + 4);
            short8 v0, v1;
            v0[0]=sbf(a0.x); v0[1]=sbf(a0.y); v0[2]=sbf(a0.z); v0[3]=sbf(a0.w);
            v0[4]=sbf(a1.x); v0[5]=sbf(a1.y); v0[6]=sbf(a1.z); v0[7]=sbf(a1.w);
            v1[0]=sbf(c0.x); v1[1]=sbf(c0.y); v1[2]=sbf(c0.z); v1[3]=sbf(c0.w);
            v1[4]=sbf(c1.x); v1[5]=sbf(c1.y); v1[6]=sbf(c1.z); v1[7]=sbf(c1.w);
            *(short8*)&As[sr * LDT + sc8] = v0;
            *(short8*)&As[(sr + 64) * LDT + sc8] = v1;
        }
        *(short8*)&Bs[sr * LDT + sc8] =
            *(const short8*)&Wt[(size_t)(bn + sr) * K + kk + sc8];
        *(short8*)&Bs[(sr + 64) * LDT + sc8] =
            *(const short8*)&Wt[(size_t)(bn + sr + 64) * K + kk + sc8];
        __syncthreads();

        short8 af[4], bfr[4];
        #pragma unroll
        for (int i = 0; i < 4; ++i) {
            af[i]  = *(const short8*)&As[(wy * 64 + i * 16 + fn) * LDT + quad * 8];
            bfr[i] = *(const short8*)&Bs[(wx * 64 + i * 16 + fn) * LDT + quad * 8];
        }
        #pragma unroll
        for (int i = 0; i < 4; ++i)
            #pragma unroll
            for (int j = 0; j < 4; ++j)
                acc[i][j] = __builtin_amdgcn_mfma_f32_16x16x32_bf16(
                    af[i], bfr[j], acc[i][j], 0, 0, 0);
    }

    #pragma unroll
    for (int j = 0; j < 4; ++j) {
        const int n = bn + wx * 64 + j * 16 + fn;
        const float bv = bias[n];
        #pragma unroll
        for (int i = 0; i < 4; ++i) {
            #pragma unroll
            for (int rg = 0; rg < 4; ++rg) {
                const int m = bm + wy * 64 + i * 16 + quad * 4 + rg;
                float v = acc[i][j][rg] + bv;
                if (RELU) v = fmaxf(v, 0.f);
                C[(size_t)m * ldc + n] = f2b(v);
            }
        }
    }
}

// ---------------------------------------------------------------------------
// MFMA flash attention v5: softmax in MFMA D-layout via DPP row reduction.
//   D-layout: lane(quad,fn) holds S[q = quad*4+rg][key = fn (s0), 16+fn (s1)].
//   A softmax row = the 16 contiguous lanes of one quad group = one DPP row,
//   so row max/sum = 4 full-rate DPP ops (no LDS, no bpermute).
//   m/l/alpha live in registers per lane (4 rows each, replicated over fn).
//   Ss/Al/Ll LDS arrays DELETED. Only P needs a cross-quad transpose:
//   key-interleaved slot layout (key k -> slot 2*(k&15)+(k>>4)) makes the
//   P write 4x ds_write_b32 (bank-clean) and the PV A-read one b128;
//   V is staged in the same slot order (one interleaved b128 write/thread),
//   so the k-permutation cancels in the PV dot product.
//   K/V double-buffer + T14 issue-early/write-late kept from v4.
// ---------------------------------------------------------------------------
__global__ __launch_bounds__(256)
void attn_v5(const bf16* __restrict__ QKV, bf16* __restrict__ Out)
{
    __shared__ __align__(16) short Ks[2][32 * 72];   // [buf][key][d]
    __shared__ __align__(16) short Vt[2][64 * 40];   // [buf][d][slot]
    __shared__ __align__(16) short Ps[4][16 * 40];   // per-wave P [q][slot] bf16

    const int tid  = threadIdx.x;
    const int wave = tid >> 6, lane = tid & 63;
    const int quad = lane >> 4, fn = lane & 15;
    const int bh = blockIdx.y;
    const int b = bh / NH, h = bh % NH;
    const int q0 = (gridDim.x - 1 - blockIdx.x) * 64;
    const int nt = q0 / 32 + 2;
    const int qwmin = q0 + wave * 16;

    const short* QKVs = (const short*)QKV;   // bit view for LDS staging

    const size_t rowQ = (size_t)(b * TS + q0 + wave * 16 + fn) * 2304 + h * 64;
    const short8 qa0 = *(const short8*)&QKV[rowQ + quad * 8];
    const short8 qa1 = *(const short8*)&QKV[rowQ + 32 + quad * 8];

    float mrow[4], lrow[4];
    #pragma unroll
    for (int rg = 0; rg < 4; ++rg) { mrow[rg] = NEG; lrow[rg] = 0.f; }
    floatx4 o[4] = {};

    const int sk = tid >> 3, sc8 = (tid & 7) * 8;
    const int vd = tid & 63, vk4 = (tid >> 6) * 4;
    const size_t gK = (size_t)(b * TS) * 2304 + 768  + h * 64 + (size_t)sk * 2304 + sc8;
    const size_t gV = (size_t)(b * TS) * 2304 + 1536 + h * 64 + vd;

    // prologue: stage tile 0 (bit copies — NaN fix preserved).
    // V interleaved: slots 2*vk4 .. 2*vk4+7 = keys vk4..vk4+3 x {lo16,hi16}.
    short8 kreg = *(const short8*)&QKVs[gK];
    short8 vreg;
    #pragma unroll
    for (int j = 0; j < 4; ++j) {
        vreg[2 * j]     = QKVs[gV + (size_t)(vk4 + j) * 2304];
        vreg[2 * j + 1] = QKVs[gV + (size_t)(vk4 + 16 + j) * 2304];
    }
    *(short8*)&Ks[0][sk * 72 + sc8]      = kreg;
    *(short8*)&Vt[0][vd * 40 + vk4 * 2]  = vreg;

    for (int t = 0; t < nt; ++t) {
        const int kk0 = t * 32;
        const int buf = t & 1;
        __syncthreads();                     // tile t staged (only barrier)

        const bool more = (t + 1 < nt);
        if (more) {                          // T14: issue next-tile loads early
            kreg = *(const short8*)&QKVs[gK + (size_t)(kk0 + 32) * 2304];
            #pragma unroll
            for (int j = 0; j < 4; ++j) {
                vreg[2 * j]     = QKVs[gV + (size_t)(kk0 + 32 + vk4 + j) * 2304];
                vreg[2 * j + 1] = QKVs[gV + (size_t)(kk0 + 48 + vk4 + j) * 2304];
            }
        }

        if (kk0 <= qwmin + 15) {             // wave-uniform: skip fully-masked
            // ---- S = Q K^T (MFMA) ----
            const short8 b00 = *(const short8*)&Ks[buf][fn * 72 + quad * 8];
            const short8 b01 = *(const short8*)&Ks[buf][fn * 72 + 32 + quad * 8];
            const short8 b10 = *(const short8*)&Ks[buf][(16 + fn) * 72 + quad * 8];
            const short8 b11 = *(const short8*)&Ks[buf][(16 + fn) * 72 + 32 + quad * 8];
            __builtin_amdgcn_s_setprio(1);
            floatx4 s0 = {}, s1 = {};
            s0 = __builtin_amdgcn_mfma_f32_16x16x32_bf16(qa0, b00, s0, 0, 0, 0);
            s0 = __builtin_amdgcn_mfma_f32_16x16x32_bf16(qa1, b01, s0, 0, 0, 0);
            s1 = __builtin_amdgcn_mfma_f32_16x16x32_bf16(qa0, b10, s1, 0, 0, 0);
            s1 = __builtin_amdgcn_mfma_f32_16x16x32_bf16(qa1, b11, s1, 0, 0, 0);
            __builtin_amdgcn_s_setprio(0);

            // scale + causal mask, in registers (D-layout)
            const int qg = q0 + wave * 16 + quad * 4;
            float v0[4], v1[4];
            if (kk0 + 31 <= qwmin) {         // interior tile: mask statically true
                #pragma unroll
                for (int rg = 0; rg < 4; ++rg) {
                    v0[rg] = s0[rg] * 0.125f;
                    v1[rg] = s1[rg] * 0.125f;
                }
            } else {
                #pragma unroll
                for (int rg = 0; rg < 4; ++rg) {
                    v0[rg] = (kk0 + fn      <= qg + rg) ? s0[rg] * 0.125f : NEG;
                    v1[rg] = (kk0 + 16 + fn <= qg + rg) ? s1[rg] * 0.125f : NEG;
                }
            }

            // ---- in-register softmax: DPP row-reduce over the 16 fn lanes ----
            float mt[4], mn2[4], p0[4], p1[4], ps[4], al[4];
            #pragma unroll
            for (int rg = 0; rg < 4; ++rg) mt[rg] = fmaxf(v0[rg], v1[rg]);
            #pragma unroll
            for (int rg = 0; rg < 4; ++rg) mt[rg] = rowmax16(mt[rg]);
            #pragma unroll
            for (int rg = 0; rg < 4; ++rg) {
                mn2[rg] = fmaxf(mrow[rg], mt[rg]);
                p0[rg] = __expf(v0[rg] - mn2[rg]);   // mn2 >= v by construction
                p1[rg] = __expf(v1[rg] - mn2[rg]);
                ps[rg] = p0[rg] + p1[rg];
            }
            #pragma unroll
            for (int rg = 0; rg < 4; ++rg) ps[rg] = rowsum16(ps[rg]);
            #pragma unroll
            for (int rg = 0; rg < 4; ++rg) {
                al[rg] = __expf(mrow[rg] - mn2[rg]);
                lrow[rg] = lrow[rg] * al[rg] + ps[rg];
                mrow[rg] = mn2[rg];
            }

            // P -> Ps in slot layout: keys fn,16+fn -> slots 2fn,2fn+1
            #pragma unroll
            for (int rg = 0; rg < 4; ++rg)
                *(unsigned*)&Ps[wave][(quad * 4 + rg) * 40 + fn * 2] =
                    pk2(p0[rg], p1[rg]);

            // rescale accumulator + PV MFMA (wave-private Ps, no barrier)
            #pragma unroll
            for (int cb = 0; cb < 4; ++cb)
                #pragma unroll
                for (int rg = 0; rg < 4; ++rg) o[cb][rg] *= al[rg];
            const short8 pf = *(const short8*)&Ps[wave][fn * 40 + quad * 8];
            __builtin_amdgcn_s_setprio(1);
            #pragma unroll
            for (int cb = 0; cb < 4; ++cb) {
                const short8 vf = *(const short8*)&Vt[buf][(cb * 16 + fn) * 40 + quad * 8];
                o[cb] = __builtin_amdgcn_mfma_f32_16x16x32_bf16(pf, vf, o[cb], 0, 0, 0);
            }
            __builtin_amdgcn_s_setprio(0);
        }

        if (more) {                          // T14: write-late into buf^1
            *(short8*)&Ks[buf ^ 1][sk * 72 + sc8]     = kreg;
            *(short8*)&Vt[buf ^ 1][vd * 40 + vk4 * 2] = vreg;
        }
    }

    #pragma unroll
    for (int cb = 0; cb < 4; ++cb)
        #pragma unroll
        for (int rg = 0; rg < 4; ++rg) {
            const float li = 1.f / fmaxf(lrow[rg], 1e-20f);
            const size_t row = (size_t)(b * TS + q0 + wave * 16 + quad * 4 + rg);
            Out[row * DM + h * 64 + cb * 16 + fn] = f2b(o[cb][rg] * li);
        }
}

// ---------------------------------------------------------------------------
__global__ __launch_bounds__(256)
void transW(const float* __restrict__ W, bf16* __restrict__ Wt, int K, int N)
{
    __shared__ float t[32][33];
    const int k0 = blockIdx.x * 32, n0 = blockIdx.y * 32;
    const int tx = threadIdx.x, ty = threadIdx.y;
    #pragma unroll
    for (int i = 0; i < 4; ++i)
        t[ty + i * 8][tx] = W[(size_t)(k0 + ty + i * 8) * N + n0 + tx];
    __syncthreads();
    #pragma unroll
    for (int i = 0; i < 4; ++i)
        Wt[(size_t)(n0 + ty + i * 8) * K + k0 + tx] = f2b(t[tx][ty + i * 8]);
}

__global__ __launch_bounds__(256)
void pack_bias(const float* __restrict__ bq, const float* __restrict__ bk,
               const float* __restrict__ bv, float* __restrict__ out)
{
    const int i = blockIdx.x * 256 + threadIdx.x;
    if (i < 3 * DM)
        out[i] = (i < DM) ? bq[i] : (i < 2 * DM) ? bk[i - DM] : bv[i - 2 * DM];
}

template <typename T1, typename T2, typename TOUT>
__global__ __launch_bounds__(256)
void add_ln(const T1* __restrict__ a, const T2* __restrict__ r, int ldr,
            const float* __restrict__ gamma, const float* __restrict__ beta,
            TOUT* __restrict__ out)
{
    const int row = blockIdx.x;
    const size_t offa = (size_t)row * DM;
    const size_t offr = (size_t)row * ldr;
    const int tid = threadIdx.x;

    float v[3];
    float s = 0.f, s2 = 0.f;
    #pragma unroll
    for (int j = 0; j < 3; ++j) {
        const int i = tid + j * 256;
        const float t = ldf(a + offa + i) + ldf(r + offr + i);
        v[j] = t; s += t; s2 += t * t;
    }
    __shared__ float red[256], red2[256];
    red[tid] = s; red2[tid] = s2;
    __syncthreads();
    #pragma unroll
    for (int st = 128; st > 0; st >>= 1) {
        if (tid < st) { red[tid] += red[tid + st]; red2[tid] += red2[tid + st]; }
        __syncthreads();
    }
    const float mu   = red[0] * (1.f / DM);
    const float var  = red2[0] * (1.f / DM) - mu * mu;
    const float rstd = rsqrtf(var + EPS);
    #pragma unroll
    for (int j = 0; j < 3; ++j) {
        const int i = tid + j * 256;
        stf(out + offa + i, (v[j] - mu) * rstd * gamma[i] + beta[i]);
    }
}

// ---------------------------------------------------------------------------
extern "C" void kernel_launch(void* const* d_in, const int* in_sizes, int n_in,
                              void* d_out, int out_size, void* d_ws, size_t ws_size,
                              hipStream_t stream)
{
    (void)in_sizes; (void)n_in; (void)out_size; (void)ws_size;

    const float* x   = (const float*)d_in[0];
    const float* wq  = (const float*)d_in[1];  const float* bq  = (const float*)d_in[2];
    const float* wk  = (const float*)d_in[3];  const float* bk  = (const float*)d_in[4];
    const float* wv  = (const float*)d_in[5];  const float* bv  = (const float*)d_in[6];
    const float* wo  = (const float*)d_in[7];  const float* bo  = (const float*)d_in[8];
    const float* w1  = (const float*)d_in[9];  const float* b1  = (const float*)d_in[10];
    const float* w2  = (const float*)d_in[11]; const float* b2  = (const float*)d_in[12];
    const float* g1  = (const float*)d_in[13]; const float* be1 = (const float*)d_in[14];
    const float* g2  = (const float*)d_in[15]; const float* be2 = (const float*)d_in[16];

    // ws layout (bf16 elems), ~59.8 MB (proven round 6):
    //   QKVb [8192][2304] = 3S | Hb = S | wbuf = 2*DFF*DM | bqkv fp32[2304]
    const size_t S = (size_t)MTOK * DM;
    bf16* QKVb = (bf16*)d_ws;
    bf16* Hb   = QKVb + 3 * S;
    bf16* wbuf = Hb + S;
    float* bqkv = (float*)(wbuf + (size_t)2 * DFF * DM);
    bf16* F1 = QKVb;              // FFN hidden chunk [4096][3072]
    bf16* Yb = QKVb + 2 * S;      // FFN out
    bf16* Pb = QKVb + DM;         // O-proj out -> K-band (dead), ld 2304
    bf16* Ao = Hb;                // attention out (dense; Hb free until LN1)

    const dim3 tblk(32, 8);
    const dim3 blk(256);

    // QKV projection
    transW<<<dim3(24, 24), tblk, 0, stream>>>(wq, wbuf,                    DM, DM);
    transW<<<dim3(24, 24), tblk, 0, stream>>>(wk, wbuf + (size_t)DM * DM,  DM, DM);
    transW<<<dim3(24, 24), tblk, 0, stream>>>(wv, wbuf + (size_t)2*DM*DM,  DM, DM);
    pack_bias<<<dim3(9), blk, 0, stream>>>(bq, bk, bv, bqkv);
    gemm_mfma<0, float><<<dim3(18, 64), blk, 0, stream>>>(
        x, DM, wbuf, bqkv, QKVb, 3 * DM, 3 * DM, DM);

    // MFMA flash attention -> Ao (dense 768)
    attn_v5<<<dim3(64, NB * NH), blk, 0, stream>>>(QKVb, Ao);

    // O-projection (Ao -> K-band), LN1 -> Hb (overwrites Ao after read)
    transW<<<dim3(24, 24), tblk, 0, stream>>>(wo, wbuf, DM, DM);
    gemm_mfma<0, bf16><<<dim3(6, 64), blk, 0, stream>>>(
        Ao, DM, wbuf, bo, Pb, 3 * DM, DM, DM);
    add_ln<float, bf16, bf16><<<dim3(MTOK), blk, 0, stream>>>(
        x, Pb, 3 * DM, g1, be1, Hb);

    // FFN (chunked over M; F1/Yb live in the dead QKVb region)
    transW<<<dim3(24, 96), tblk, 0, stream>>>(w1, wbuf, DM, DFF);
    bf16* w2t = wbuf + (size_t)DFF * DM;
    transW<<<dim3(96, 24), tblk, 0, stream>>>(w2, w2t, DFF, DM);
    for (int m0 = 0; m0 < MTOK; m0 += 4096) {
        gemm_mfma<1, bf16><<<dim3(24, 32), blk, 0, stream>>>(
            Hb + (size_t)m0 * DM, DM, wbuf, b1, F1, DFF, DFF, DM);
        gemm_mfma<0, bf16><<<dim3(6, 32), blk, 0, stream>>>(
            F1, DFF, w2t, b2, Yb + (size_t)m0 * DM, DM, DM, DFF);
    }

    add_ln<bf16, bf16, float><<<dim3(MTOK), blk, 0, stream>>>(
        Hb, Yb, DM, g2, be2, (float*)d_out);
}

// Round 4
// 728.160 us; speedup vs baseline: 1.0812x; 1.0812x over previous
//
#include <hip/hip_runtime.h>
#include <hip/hip_bf16.h>

typedef __hip_bfloat16 bf16;
typedef __attribute__((ext_vector_type(8))) short short8;
typedef __attribute__((ext_vector_type(4))) short short4b;
typedef __attribute__((ext_vector_type(4))) float floatx4;

#define DM   768
#define NH   12
#define DH   64
#define DFF  3072
#define TS   4096
#define NB   2
#define MTOK (NB * TS)
#define EPS  1e-5f
#define NEG  -30000.0f

__device__ __forceinline__ float b2f(bf16 v)  { return __bfloat162float(v); }
__device__ __forceinline__ bf16  f2b(float v) { return __float2bfloat16(v); }
__device__ __forceinline__ short sbf(float x) { bf16 b = __float2bfloat16(x); return *(short*)&b; }
__device__ __forceinline__ float ldf(const float* p) { return *p; }
__device__ __forceinline__ float ldf(const bf16*  p) { return b2f(*p); }
__device__ __forceinline__ void stf(float* p, float v) { *p = v; }
__device__ __forceinline__ void stf(bf16*  p, float v) { *p = f2b(v); }

// async global->LDS DMA, 16B per lane. LDS dest is wave-uniform base +
// lane*16 (HW rule); global src is per-lane. Completion drained by the
// vmcnt(0) the compiler emits before __syncthreads().
__device__ __forceinline__ void gl2lds(const bf16* g, short* l) {
    __builtin_amdgcn_global_load_lds(
        (const __attribute__((address_space(1))) void*)g,
        (__attribute__((address_space(3))) void*)l, 16, 0, 0);
}

// ---------------------------------------------------------------------------
// MFMA GEMM with global_load_lds staging (m97 structure).
//   LDS tiles are LINEAR [128][32] bf16 (global_load_lds requires linear
//   dest). Per K-step per wave: 4 DMA issues (A chunks w,w+4; B chunks
//   w,w+4; each = 16 rows x 64B = 1024B = 64 lanes x 16B), 2 barriers,
//   8 ds_read_b128, 16 MFMA. Staging VALU ~= 0 (the round-4 theory).
//   A must be bf16 (fp32 inputs pre-converted by xcvt).
// ---------------------------------------------------------------------------
template <int RELU>
__global__ __launch_bounds__(256)
void gemm_lds(const bf16* __restrict__ A, int lda, const bf16* __restrict__ Wt,
              const float* __restrict__ bias, bf16* __restrict__ C, int ldc,
              int N, int K)
{
    __shared__ __align__(16) short As[128 * 32];
    __shared__ __align__(16) short Bs[128 * 32];

    const int tid  = threadIdx.x;
    const int wave = tid >> 6, lane = tid & 63;
    const int wx = wave & 1, wy = wave >> 1;
    const int quad = lane >> 4, fn = lane & 15;
    const int bm = blockIdx.y * 128, bn = blockIdx.x * 128;
    const int l4 = lane >> 2, l8 = (lane & 3) * 8;   // lane -> (row, col8) in chunk

    // per-lane global sources for the 4 chunks this wave stages each step
    const bf16* gA0 = A  + (size_t)(bm + wave * 16       + l4) * lda + l8;
    const bf16* gA1 = A  + (size_t)(bm + (wave + 4) * 16 + l4) * lda + l8;
    const bf16* gB0 = Wt + (size_t)(bn + wave * 16       + l4) * K   + l8;
    const bf16* gB1 = Wt + (size_t)(bn + (wave + 4) * 16 + l4) * K   + l8;
    // wave-uniform LDS chunk bases (16 rows x 32 shorts = 512 shorts)
    short* lA0 = &As[wave * 512];
    short* lA1 = &As[(wave + 4) * 512];
    short* lB0 = &Bs[wave * 512];
    short* lB1 = &Bs[(wave + 4) * 512];

    floatx4 acc[4][4] = {};

    for (int kk = 0; kk < K; kk += 32) {
        __syncthreads();                 // previous step's reads done
        gl2lds(gA0 + kk, lA0);
        gl2lds(gA1 + kk, lA1);
        gl2lds(gB0 + kk, lB0);
        gl2lds(gB1 + kk, lB1);
        __syncthreads();                 // drains vmcnt(0): tiles landed

        short8 af[4], bfr[4];
        #pragma unroll
        for (int i = 0; i < 4; ++i) {
            af[i]  = *(const short8*)&As[(wy * 64 + i * 16 + fn) * 32 + quad * 8];
            bfr[i] = *(const short8*)&Bs[(wx * 64 + i * 16 + fn) * 32 + quad * 8];
        }
        #pragma unroll
        for (int i = 0; i < 4; ++i)
            #pragma unroll
            for (int j = 0; j < 4; ++j)
                acc[i][j] = __builtin_amdgcn_mfma_f32_16x16x32_bf16(
                    af[i], bfr[j], acc[i][j], 0, 0, 0);
    }

    #pragma unroll
    for (int j = 0; j < 4; ++j) {
        const int n = bn + wx * 64 + j * 16 + fn;
        const float bv = bias[n];
        #pragma unroll
        for (int i = 0; i < 4; ++i) {
            #pragma unroll
            for (int rg = 0; rg < 4; ++rg) {
                const int m = bm + wy * 64 + i * 16 + quad * 4 + rg;
                float v = acc[i][j][rg] + bv;
                if (RELU) v = fmaxf(v, 0.f);
                C[(size_t)m * ldc + n] = f2b(v);
            }
        }
    }
}

// x (fp32) -> bf16, vectorized 8/thread. 6291456 elems = 3072 blocks exactly.
__global__ __launch_bounds__(256)
void xcvt(const float* __restrict__ x, bf16* __restrict__ xb)
{
    const size_t i = ((size_t)blockIdx.x * 256 + threadIdx.x) * 8;
    const float4 a = *(const float4*)&x[i];
    const float4 b = *(const float4*)&x[i + 4];
    short8 v;
    v[0]=sbf(a.x); v[1]=sbf(a.y); v[2]=sbf(a.z); v[3]=sbf(a.w);
    v[4]=sbf(b.x); v[5]=sbf(b.y); v[6]=sbf(b.z); v[7]=sbf(b.w);
    *(short8*)&xb[i] = v;
}

// ---------------------------------------------------------------------------
// MFMA flash attention v4 (PROVEN round 2, 331 us) — unchanged revert.
// ---------------------------------------------------------------------------
__global__ __launch_bounds__(256)
void attn_v4(const bf16* __restrict__ QKV, bf16* __restrict__ Out)
{
    __shared__ __align__(16) short Ks[2][32 * 72];   // [buf][key][d]
    __shared__ __align__(16) short Vt[2][64 * 40];   // [buf][d][key]
    __shared__ __align__(16) float Ss[4][16 * 36];   // per-wave S [q][key] fp32
    __shared__ __align__(16) short Ps[4][16 * 40];   // per-wave P [q][key] bf16
    __shared__ float Al[4][16];                      // per-row alpha
    __shared__ float Ll[4][16];                      // per-row l

    const int tid  = threadIdx.x;
    const int wave = tid >> 6, lane = tid & 63;
    const int quad = lane >> 4, fn = lane & 15;
    const int bh = blockIdx.y;
    const int b = bh / NH, h = bh % NH;
    const int q0 = (gridDim.x - 1 - blockIdx.x) * 64;
    const int nt = q0 / 32 + 2;
    const int qwmin = q0 + wave * 16;

    const int orow = lane >> 2;
    const int okey = (lane & 3) * 8;

    const short* QKVs = (const short*)QKV;   // bit view for LDS staging

    const size_t rowQ = (size_t)(b * TS + q0 + wave * 16 + fn) * 2304 + h * 64;
    const short8 qa0 = *(const short8*)&QKV[rowQ + quad * 8];
    const short8 qa1 = *(const short8*)&QKV[rowQ + 32 + quad * 8];

    float mrow = NEG, lrow = 0.f;
    floatx4 o[4] = {};

    const int sk = tid >> 3, sc8 = (tid & 7) * 8;
    const int vd = tid & 63, vk4 = (tid >> 6) * 4;
    const size_t gK = (size_t)(b * TS) * 2304 + 768  + h * 64 + (size_t)sk * 2304 + sc8;
    const size_t gV = (size_t)(b * TS) * 2304 + 1536 + h * 64 + vd;

    // prologue: stage tile 0 (bit copies — NaN fix preserved)
    short8 kreg = *(const short8*)&QKVs[gK];
    short4b va, vb;
    #pragma unroll
    for (int j = 0; j < 4; ++j) {
        va[j] = QKVs[gV + (size_t)(vk4 + j) * 2304];
        vb[j] = QKVs[gV + (size_t)(vk4 + 16 + j) * 2304];
    }
    *(short8*)&Ks[0][sk * 72 + sc8]           = kreg;
    *(short4b*)&Vt[0][vd * 40 + vk4]          = va;
    *(short4b*)&Vt[0][vd * 40 + 16 + vk4]     = vb;

    for (int t = 0; t < nt; ++t) {
        const int kk0 = t * 32;
        const int buf = t & 1;
        __syncthreads();                     // tile t staged (only barrier)

        const bool more = (t + 1 < nt);
        if (more) {                          // T14: issue next-tile loads early
            kreg = *(const short8*)&QKVs[gK + (size_t)(kk0 + 32) * 2304];
            #pragma unroll
            for (int j = 0; j < 4; ++j) {
                va[j] = QKVs[gV + (size_t)(kk0 + 32 + vk4 + j) * 2304];
                vb[j] = QKVs[gV + (size_t)(kk0 + 48 + vk4 + j) * 2304];
            }
        }

        if (kk0 <= qwmin + 15) {             // wave-uniform: skip fully-masked
            // ---- S = Q K^T (MFMA) ----
            const short8 b00 = *(const short8*)&Ks[buf][fn * 72 + quad * 8];
            const short8 b01 = *(const short8*)&Ks[buf][fn * 72 + 32 + quad * 8];
            const short8 b10 = *(const short8*)&Ks[buf][(16 + fn) * 72 + quad * 8];
            const short8 b11 = *(const short8*)&Ks[buf][(16 + fn) * 72 + 32 + quad * 8];
            __builtin_amdgcn_s_setprio(1);
            floatx4 s0 = {}, s1 = {};
            s0 = __builtin_amdgcn_mfma_f32_16x16x32_bf16(qa0, b00, s0, 0, 0, 0);
            s0 = __builtin_amdgcn_mfma_f32_16x16x32_bf16(qa1, b01, s0, 0, 0, 0);
            s1 = __builtin_amdgcn_mfma_f32_16x16x32_bf16(qa0, b10, s1, 0, 0, 0);
            s1 = __builtin_amdgcn_mfma_f32_16x16x32_bf16(qa1, b11, s1, 0, 0, 0);
            __builtin_amdgcn_s_setprio(0);

            // scale + mask, S -> wave-private LDS (no barrier needed)
            const int qg = q0 + wave * 16 + quad * 4;
            if (kk0 + 31 <= qwmin) {         // interior tile: mask statically true
                #pragma unroll
                for (int rg = 0; rg < 4; ++rg) {
                    Ss[wave][(quad * 4 + rg) * 36 + fn]      = s0[rg] * 0.125f;
                    Ss[wave][(quad * 4 + rg) * 36 + 16 + fn] = s1[rg] * 0.125f;
                }
            } else {
                #pragma unroll
                for (int rg = 0; rg < 4; ++rg) {
                    const float v0 = (kk0 + fn      <= qg + rg) ? s0[rg] * 0.125f : NEG;
                    const float v1 = (kk0 + 16 + fn <= qg + rg) ? s1[rg] * 0.125f : NEG;
                    Ss[wave][(quad * 4 + rg) * 36 + fn]      = v0;
                    Ss[wave][(quad * 4 + rg) * 36 + 16 + fn] = v1;
                }
            }

            // ---- LDS softmax (lane owns row lane>>2, 8-key slice) ----
            float sv[8];
            *(float4*)&sv[0] = *(const float4*)&Ss[wave][orow * 36 + okey];
            *(float4*)&sv[4] = *(const float4*)&Ss[wave][orow * 36 + okey + 4];
            float mx = sv[0];
            #pragma unroll
            for (int j = 1; j < 8; ++j) mx = fmaxf(mx, sv[j]);
            mx = fmaxf(mx, __shfl_xor(mx, 1, 64));
            mx = fmaxf(mx, __shfl_xor(mx, 2, 64));
            const float mn2 = fmaxf(mrow, mx);
            float ps = 0.f;
            short8 pb;
            #pragma unroll
            for (int j = 0; j < 8; ++j) {
                const float p = __expf(fminf(sv[j] - mn2, 0.f));
                ps += p;
                pb[j] = sbf(p);
            }
            ps += __shfl_xor(ps, 1, 64);
            ps += __shfl_xor(ps, 2, 64);
            const float cr = __expf(fminf(mrow - mn2, 0.f));
            lrow = lrow * cr + ps;
            mrow = mn2;
            *(short8*)&Ps[wave][orow * 40 + okey] = pb;
            if ((lane & 3) == 0) { Al[wave][orow] = cr; Ll[wave][orow] = lrow; }

            // ---- rescale accumulator + PV MFMA (wave-private, no barrier) ----
            float al[4];
            #pragma unroll
            for (int rg = 0; rg < 4; ++rg) al[rg] = Al[wave][quad * 4 + rg];
            #pragma unroll
            for (int cb = 0; cb < 4; ++cb)
                #pragma unroll
                for (int rg = 0; rg < 4; ++rg) o[cb][rg] *= al[rg];
            const short8 pf = *(const short8*)&Ps[wave][fn * 40 + quad * 8];
            __builtin_amdgcn_s_setprio(1);
            #pragma unroll
            for (int cb = 0; cb < 4; ++cb) {
                const short8 vf = *(const short8*)&Vt[buf][(cb * 16 + fn) * 40 + quad * 8];
                o[cb] = __builtin_amdgcn_mfma_f32_16x16x32_bf16(pf, vf, o[cb], 0, 0, 0);
            }
            __builtin_amdgcn_s_setprio(0);
        }

        if (more) {                          // T14: write-late into buf^1
            *(short8*)&Ks[buf ^ 1][sk * 72 + sc8]       = kreg;
            *(short4b*)&Vt[buf ^ 1][vd * 40 + vk4]      = va;
            *(short4b*)&Vt[buf ^ 1][vd * 40 + 16 + vk4] = vb;
        }
    }

    float li[4];
    #pragma unroll
    for (int rg = 0; rg < 4; ++rg)
        li[rg] = 1.f / fmaxf(Ll[wave][quad * 4 + rg], 1e-20f);
    #pragma unroll
    for (int cb = 0; cb < 4; ++cb)
        #pragma unroll
        for (int rg = 0; rg < 4; ++rg) {
            const size_t row = (size_t)(b * TS + q0 + wave * 16 + quad * 4 + rg);
            Out[row * DM + h * 64 + cb * 16 + fn] = f2b(o[cb][rg] * li[rg]);
        }
}

// ---------------------------------------------------------------------------
__global__ __launch_bounds__(256)
void transW(const float* __restrict__ W, bf16* __restrict__ Wt, int K, int N)
{
    __shared__ float t[32][33];
    const int k0 = blockIdx.x * 32, n0 = blockIdx.y * 32;
    const int tx = threadIdx.x, ty = threadIdx.y;
    #pragma unroll
    for (int i = 0; i < 4; ++i)
        t[ty + i * 8][tx] = W[(size_t)(k0 + ty + i * 8) * N + n0 + tx];
    __syncthreads();
    #pragma unroll
    for (int i = 0; i < 4; ++i)
        Wt[(size_t)(n0 + ty + i * 8) * K + k0 + tx] = f2b(t[tx][ty + i * 8]);
}

__global__ __launch_bounds__(256)
void pack_bias(const float* __restrict__ bq, const float* __restrict__ bk,
               const float* __restrict__ bv, float* __restrict__ out)
{
    const int i = blockIdx.x * 256 + threadIdx.x;
    if (i < 3 * DM)
        out[i] = (i < DM) ? bq[i] : (i < 2 * DM) ? bk[i - DM] : bv[i - 2 * DM];
}

template <typename T1, typename T2, typename TOUT>
__global__ __launch_bounds__(256)
void add_ln(const T1* __restrict__ a, const T2* __restrict__ r, int ldr,
            const float* __restrict__ gamma, const float* __restrict__ beta,
            TOUT* __restrict__ out)
{
    const int row = blockIdx.x;
    const size_t offa = (size_t)row * DM;
    const size_t offr = (size_t)row * ldr;
    const int tid = threadIdx.x;

    float v[3];
    float s = 0.f, s2 = 0.f;
    #pragma unroll
    for (int j = 0; j < 3; ++j) {
        const int i = tid + j * 256;
        const float t = ldf(a + offa + i) + ldf(r + offr + i);
        v[j] = t; s += t; s2 += t * t;
    }
    __shared__ float red[256], red2[256];
    red[tid] = s; red2[tid] = s2;
    __syncthreads();
    #pragma unroll
    for (int st = 128; st > 0; st >>= 1) {
        if (tid < st) { red[tid] += red[tid + st]; red2[tid] += red2[tid + st]; }
        __syncthreads();
    }
    const float mu   = red[0] * (1.f / DM);
    const float var  = red2[0] * (1.f / DM) - mu * mu;
    const float rstd = rsqrtf(var + EPS);
    #pragma unroll
    for (int j = 0; j < 3; ++j) {
        const int i = tid + j * 256;
        stf(out + offa + i, (v[j] - mu) * rstd * gamma[i] + beta[i]);
    }
}

// ---------------------------------------------------------------------------
extern "C" void kernel_launch(void* const* d_in, const int* in_sizes, int n_in,
                              void* d_out, int out_size, void* d_ws, size_t ws_size,
                              hipStream_t stream)
{
    (void)in_sizes; (void)n_in; (void)out_size; (void)ws_size;

    const float* x   = (const float*)d_in[0];
    const float* wq  = (const float*)d_in[1];  const float* bq  = (const float*)d_in[2];
    const float* wk  = (const float*)d_in[3];  const float* bk  = (const float*)d_in[4];
    const float* wv  = (const float*)d_in[5];  const float* bv  = (const float*)d_in[6];
    const float* wo  = (const float*)d_in[7];  const float* bo  = (const float*)d_in[8];
    const float* w1  = (const float*)d_in[9];  const float* b1  = (const float*)d_in[10];
    const float* w2  = (const float*)d_in[11]; const float* b2  = (const float*)d_in[12];
    const float* g1  = (const float*)d_in[13]; const float* be1 = (const float*)d_in[14];
    const float* g2  = (const float*)d_in[15]; const float* be2 = (const float*)d_in[16];

    // ws layout (bf16 elems), ~59.8 MB (proven round 6):
    //   QKVb [8192][2304] = 3S | Hb = S | wbuf = 2*DFF*DM | bqkv fp32[2304]
    const size_t S = (size_t)MTOK * DM;
    bf16* QKVb = (bf16*)d_ws;
    bf16* Hb   = QKVb + 3 * S;
    bf16* wbuf = Hb + S;
    float* bqkv = (float*)(wbuf + (size_t)2 * DFF * DM);
    bf16* F1 = QKVb;              // FFN hidden chunk [4096][3072]
    bf16* Yb = QKVb + 2 * S;      // FFN out
    bf16* Pb = QKVb + DM;         // O-proj out -> K-band (dead), ld 2304
    bf16* Ao = Hb;                // attention out (dense; Hb free until LN1)
    bf16* xb = Hb;                // x as bf16 (dead after QKV proj; Hb free)

    const dim3 tblk(32, 8);
    const dim3 blk(256);

    // x -> bf16 (enables global_load_lds staging in the QKV GEMM)
    xcvt<<<dim3(3072), blk, 0, stream>>>(x, xb);

    // QKV projection
    transW<<<dim3(24, 24), tblk, 0, stream>>>(wq, wbuf,                    DM, DM);
    transW<<<dim3(24, 24), tblk, 0, stream>>>(wk, wbuf + (size_t)DM * DM,  DM, DM);
    transW<<<dim3(24, 24), tblk, 0, stream>>>(wv, wbuf + (size_t)2*DM*DM,  DM, DM);
    pack_bias<<<dim3(9), blk, 0, stream>>>(bq, bk, bv, bqkv);
    gemm_lds<0><<<dim3(18, 64), blk, 0, stream>>>(
        xb, DM, wbuf, bqkv, QKVb, 3 * DM, 3 * DM, DM);

    // MFMA flash attention -> Ao (dense 768; overwrites dead xb)
    attn_v4<<<dim3(64, NB * NH), blk, 0, stream>>>(QKVb, Ao);

    // O-projection (Ao -> K-band), LN1 -> Hb (overwrites Ao after read)
    transW<<<dim3(24, 24), tblk, 0, stream>>>(wo, wbuf, DM, DM);
    gemm_lds<0><<<dim3(6, 64), blk, 0, stream>>>(
        Ao, DM, wbuf, bo, Pb, 3 * DM, DM, DM);
    add_ln<float, bf16, bf16><<<dim3(MTOK), blk, 0, stream>>>(
        x, Pb, 3 * DM, g1, be1, Hb);

    // FFN (chunked over M; F1/Yb live in the dead QKVb region)
    transW<<<dim3(24, 96), tblk, 0, stream>>>(w1, wbuf, DM, DFF);
    bf16* w2t = wbuf + (size_t)DFF * DM;
    transW<<<dim3(96, 24), tblk, 0, stream>>>(w2, w2t, DFF, DM);
    for (int m0 = 0; m0 < MTOK; m0 += 4096) {
        gemm_lds<1><<<dim3(24, 32), blk, 0, stream>>>(
            Hb + (size_t)m0 * DM, DM, wbuf, b1, F1, DFF, DFF, DM);
        gemm_lds<0><<<dim3(6, 32), blk, 0, stream>>>(
            F1, DFF, w2t, b2, Yb + (size_t)m0 * DM, DM, DM, DFF);
    }

    add_ln<bf16, bf16, float><<<dim3(MTOK), blk, 0, stream>>>(
        Hb, Yb, DM, g2, be2, (float*)d_out);
}

// Round 5
// 685.464 us; speedup vs baseline: 1.1485x; 1.0623x over previous
//
#include <hip/hip_runtime.h>
#include <hip/hip_bf16.h>

typedef __hip_bfloat16 bf16;
typedef __attribute__((ext_vector_type(8))) short short8;
typedef __attribute__((ext_vector_type(4))) short short4b;
typedef __attribute__((ext_vector_type(4))) float floatx4;

#define DM   768
#define NH   12
#define DH   64
#define DFF  3072
#define TS   4096
#define NB   2
#define MTOK (NB * TS)
#define EPS  1e-5f
#define NEG  -30000.0f

__device__ __forceinline__ float b2f(bf16 v)  { return __bfloat162float(v); }
__device__ __forceinline__ bf16  f2b(float v) { return __float2bfloat16(v); }
__device__ __forceinline__ short sbf(float x) { bf16 b = __float2bfloat16(x); return *(short*)&b; }
__device__ __forceinline__ float ldf(const float* p) { return *p; }
__device__ __forceinline__ float ldf(const bf16*  p) { return b2f(*p); }
__device__ __forceinline__ void stf(float* p, float v) { *p = v; }
__device__ __forceinline__ void stf(bf16*  p, float v) { *p = f2b(v); }

// async global->LDS DMA, 16B per lane. LDS dest is wave-uniform base +
// lane*16 (HW rule); global src is per-lane.
__device__ __forceinline__ void gl2lds(const bf16* g, short* l) {
    __builtin_amdgcn_global_load_lds(
        (const __attribute__((address_space(1))) void*)g,
        (__attribute__((address_space(3))) void*)l, 16, 0, 0);
}

// ---------------------------------------------------------------------------
// MFMA GEMM with global_load_lds staging (round 4, kept).
// ---------------------------------------------------------------------------
template <int RELU>
__global__ __launch_bounds__(256)
void gemm_lds(const bf16* __restrict__ A, int lda, const bf16* __restrict__ Wt,
              const float* __restrict__ bias, bf16* __restrict__ C, int ldc,
              int N, int K)
{
    __shared__ __align__(16) short As[128 * 32];
    __shared__ __align__(16) short Bs[128 * 32];

    const int tid  = threadIdx.x;
    const int wave = tid >> 6, lane = tid & 63;
    const int wx = wave & 1, wy = wave >> 1;
    const int quad = lane >> 4, fn = lane & 15;
    const int bm = blockIdx.y * 128, bn = blockIdx.x * 128;
    const int l4 = lane >> 2, l8 = (lane & 3) * 8;

    const bf16* gA0 = A  + (size_t)(bm + wave * 16       + l4) * lda + l8;
    const bf16* gA1 = A  + (size_t)(bm + (wave + 4) * 16 + l4) * lda + l8;
    const bf16* gB0 = Wt + (size_t)(bn + wave * 16       + l4) * K   + l8;
    const bf16* gB1 = Wt + (size_t)(bn + (wave + 4) * 16 + l4) * K   + l8;
    short* lA0 = &As[wave * 512];
    short* lA1 = &As[(wave + 4) * 512];
    short* lB0 = &Bs[wave * 512];
    short* lB1 = &Bs[(wave + 4) * 512];

    floatx4 acc[4][4] = {};

    for (int kk = 0; kk < K; kk += 32) {
        __syncthreads();
        gl2lds(gA0 + kk, lA0);
        gl2lds(gA1 + kk, lA1);
        gl2lds(gB0 + kk, lB0);
        gl2lds(gB1 + kk, lB1);
        __syncthreads();

        short8 af[4], bfr[4];
        #pragma unroll
        for (int i = 0; i < 4; ++i) {
            af[i]  = *(const short8*)&As[(wy * 64 + i * 16 + fn) * 32 + quad * 8];
            bfr[i] = *(const short8*)&Bs[(wx * 64 + i * 16 + fn) * 32 + quad * 8];
        }
        #pragma unroll
        for (int i = 0; i < 4; ++i)
            #pragma unroll
            for (int j = 0; j < 4; ++j)
                acc[i][j] = __builtin_amdgcn_mfma_f32_16x16x32_bf16(
                    af[i], bfr[j], acc[i][j], 0, 0, 0);
    }

    #pragma unroll
    for (int j = 0; j < 4; ++j) {
        const int n = bn + wx * 64 + j * 16 + fn;
        const float bv = bias[n];
        #pragma unroll
        for (int i = 0; i < 4; ++i) {
            #pragma unroll
            for (int rg = 0; rg < 4; ++rg) {
                const int m = bm + wy * 64 + i * 16 + quad * 4 + rg;
                float v = acc[i][j][rg] + bv;
                if (RELU) v = fmaxf(v, 0.f);
                C[(size_t)m * ldc + n] = f2b(v);
            }
        }
    }
}

// x (fp32) -> bf16, vectorized 8/thread.
__global__ __launch_bounds__(256)
void xcvt(const float* __restrict__ x, bf16* __restrict__ xb)
{
    const size_t i = ((size_t)blockIdx.x * 256 + threadIdx.x) * 8;
    const float4 a = *(const float4*)&x[i];
    const float4 b = *(const float4*)&x[i + 4];
    short8 v;
    v[0]=sbf(a.x); v[1]=sbf(a.y); v[2]=sbf(a.z); v[3]=sbf(a.w);
    v[4]=sbf(b.x); v[5]=sbf(b.y); v[6]=sbf(b.z); v[7]=sbf(b.w);
    *(short8*)&xb[i] = v;
}

// ---------------------------------------------------------------------------
// MFMA flash attention v6 = v4 dataflow with KVBLK=64.
//   One softmax chain (Ss round-trip -> reduce -> m/l update -> Al/Ll ->
//   Ps round-trip) per 64 keys instead of per 32: the latency-bound serial
//   chain count halves; MFMA count, staging bytes and barriers-per-key are
//   unchanged. Single K/V buffer, register prefetch (T14 issue-early:
//   loads for t+1 issued before the compute barrier, land during compute).
//   All per-wave LDS (Ss/Ps/Al/Ll) barrier-free as proven in v4.
// ---------------------------------------------------------------------------
__global__ __launch_bounds__(256)
void attn_v6(const bf16* __restrict__ QKV, bf16* __restrict__ Out)
{
    __shared__ __align__(16) short Ks[64 * 72];      // [key][d]
    __shared__ __align__(16) short Vt[64 * 72];      // [d][key]
    __shared__ __align__(16) float Ss[4][16 * 68];   // per-wave S [q][key] fp32
    __shared__ __align__(16) short Ps[4][16 * 72];   // per-wave P [q][key] bf16
    __shared__ float Al[4][16];                      // per-row alpha
    __shared__ float Ll[4][16];                      // per-row l

    const int tid  = threadIdx.x;
    const int wave = tid >> 6, lane = tid & 63;
    const int quad = lane >> 4, fn = lane & 15;
    const int bh = blockIdx.y;
    const int b = bh / NH, h = bh % NH;
    const int q0 = (gridDim.x - 1 - blockIdx.x) * 64;
    const int nt = q0 / 64 + 1;              // 64-key tiles
    const int qwmin = q0 + wave * 16;

    const int orow = lane >> 2;              // 0..15 (owned q-row)
    const int okey = (lane & 3) * 16;        // 16-key slice base

    const short* QKVs = (const short*)QKV;   // bit view for LDS staging

    const size_t rowQ = (size_t)(b * TS + q0 + wave * 16 + fn) * 2304 + h * 64;
    const short8 qa0 = *(const short8*)&QKV[rowQ + quad * 8];
    const short8 qa1 = *(const short8*)&QKV[rowQ + 32 + quad * 8];

    float mrow = NEG, lrow = 0.f;
    floatx4 o[4] = {};

    const int sk = tid >> 3, sc8 = (tid & 7) * 8;    // K staging: 32 rows/pass
    const int vd = tid & 63, vk4 = (tid >> 6) * 4;   // V staging: 4+4+4+4 keys
    const size_t gK = (size_t)(b * TS) * 2304 + 768  + h * 64 + (size_t)sk * 2304 + sc8;
    const size_t gV = (size_t)(b * TS) * 2304 + 1536 + h * 64 + vd;

    // prologue: load tile 0 into registers (bit copies — NaN fix preserved)
    short8 kr0 = *(const short8*)&QKVs[gK];
    short8 kr1 = *(const short8*)&QKVs[gK + (size_t)32 * 2304];
    short4b vr0, vr1, vr2, vr3;
    #pragma unroll
    for (int j = 0; j < 4; ++j) {
        vr0[j] = QKVs[gV + (size_t)(vk4 + j) * 2304];
        vr1[j] = QKVs[gV + (size_t)(16 + vk4 + j) * 2304];
        vr2[j] = QKVs[gV + (size_t)(32 + vk4 + j) * 2304];
        vr3[j] = QKVs[gV + (size_t)(48 + vk4 + j) * 2304];
    }

    for (int t = 0; t < nt; ++t) {
        const int kk0 = t * 64;
        __syncthreads();                 // all reads of tile t-1 done
        *(short8*)&Ks[sk * 72 + sc8]        = kr0;
        *(short8*)&Ks[(sk + 32) * 72 + sc8] = kr1;
        *(short4b*)&Vt[vd * 72 + vk4]       = vr0;
        *(short4b*)&Vt[vd * 72 + 16 + vk4]  = vr1;
        *(short4b*)&Vt[vd * 72 + 32 + vk4]  = vr2;
        *(short4b*)&Vt[vd * 72 + 48 + vk4]  = vr3;
        if (t + 1 < nt) {                // T14: issue next-tile loads early
            const size_t nk = (size_t)(kk0 + 64) * 2304;
            kr0 = *(const short8*)&QKVs[gK + nk];
            kr1 = *(const short8*)&QKVs[gK + nk + (size_t)32 * 2304];
            #pragma unroll
            for (int j = 0; j < 4; ++j) {
                vr0[j] = QKVs[gV + nk + (size_t)(vk4 + j) * 2304];
                vr1[j] = QKVs[gV + nk + (size_t)(16 + vk4 + j) * 2304];
                vr2[j] = QKVs[gV + nk + (size_t)(32 + vk4 + j) * 2304];
                vr3[j] = QKVs[gV + nk + (size_t)(48 + vk4 + j) * 2304];
            }
        }
        __syncthreads();                 // tile t staged

        if (kk0 > qwmin + 15) continue;  // fully masked for this wave
                                         // (both barriers already executed)

        // ---- S = Q K^T : 4 sub-tiles of 16 keys, 8 MFMA ----
        __builtin_amdgcn_s_setprio(1);
        floatx4 s[4] = {};
        #pragma unroll
        for (int ks = 0; ks < 4; ++ks) {
            const short8 ka = *(const short8*)&Ks[(ks * 16 + fn) * 72 + quad * 8];
            const short8 kb = *(const short8*)&Ks[(ks * 16 + fn) * 72 + 32 + quad * 8];
            s[ks] = __builtin_amdgcn_mfma_f32_16x16x32_bf16(qa0, ka, s[ks], 0, 0, 0);
            s[ks] = __builtin_amdgcn_mfma_f32_16x16x32_bf16(qa1, kb, s[ks], 0, 0, 0);
        }
        __builtin_amdgcn_s_setprio(0);

        // scale + mask, S -> wave-private LDS (no barrier needed)
        const int qg = q0 + wave * 16 + quad * 4;
        if (kk0 + 63 <= qwmin) {         // interior tile: mask statically true
            #pragma unroll
            for (int ks = 0; ks < 4; ++ks)
                #pragma unroll
                for (int rg = 0; rg < 4; ++rg)
                    Ss[wave][(quad * 4 + rg) * 68 + ks * 16 + fn] = s[ks][rg] * 0.125f;
        } else {
            #pragma unroll
            for (int ks = 0; ks < 4; ++ks)
                #pragma unroll
                for (int rg = 0; rg < 4; ++rg) {
                    const float v = (kk0 + ks * 16 + fn <= qg + rg)
                                        ? s[ks][rg] * 0.125f : NEG;
                    Ss[wave][(quad * 4 + rg) * 68 + ks * 16 + fn] = v;
                }
        }

        // ---- LDS softmax (lane owns row lane>>2, 16-key slice) ----
        float sv[16];
        *(float4*)&sv[0]  = *(const float4*)&Ss[wave][orow * 68 + okey];
        *(float4*)&sv[4]  = *(const float4*)&Ss[wave][orow * 68 + okey + 4];
        *(float4*)&sv[8]  = *(const float4*)&Ss[wave][orow * 68 + okey + 8];
        *(float4*)&sv[12] = *(const float4*)&Ss[wave][orow * 68 + okey + 12];
        float mx = sv[0];
        #pragma unroll
        for (int j = 1; j < 16; ++j) mx = fmaxf(mx, sv[j]);
        mx = fmaxf(mx, __shfl_xor(mx, 1, 64));
        mx = fmaxf(mx, __shfl_xor(mx, 2, 64));
        const float mn2 = fmaxf(mrow, mx);
        float ps = 0.f;
        short8 pb0, pb1;
        #pragma unroll
        for (int j = 0; j < 8; ++j) {
            const float p = __expf(fminf(sv[j] - mn2, 0.f));
            ps += p;
            pb0[j] = sbf(p);
        }
        #pragma unroll
        for (int j = 0; j < 8; ++j) {
            const float p = __expf(fminf(sv[8 + j] - mn2, 0.f));
            ps += p;
            pb1[j] = sbf(p);
        }
        ps += __shfl_xor(ps, 1, 64);
        ps += __shfl_xor(ps, 2, 64);
        const float cr = __expf(fminf(mrow - mn2, 0.f));
        lrow = lrow * cr + ps;
        mrow = mn2;
        *(short8*)&Ps[wave][orow * 72 + okey]     = pb0;
        *(short8*)&Ps[wave][orow * 72 + okey + 8] = pb1;
        if ((lane & 3) == 0) { Al[wave][orow] = cr; Ll[wave][orow] = lrow; }

        // ---- rescale accumulator + PV MFMA (wave-private, no barrier) ----
        float al[4];
        #pragma unroll
        for (int rg = 0; rg < 4; ++rg) al[rg] = Al[wave][quad * 4 + rg];
        #pragma unroll
        for (int cb = 0; cb < 4; ++cb)
            #pragma unroll
            for (int rg = 0; rg < 4; ++rg) o[cb][rg] *= al[rg];
        const short8 pf0 = *(const short8*)&Ps[wave][fn * 72 + quad * 8];
        const short8 pf1 = *(const short8*)&Ps[wave][fn * 72 + 32 + quad * 8];
        __builtin_amdgcn_s_setprio(1);
        #pragma unroll
        for (int cb = 0; cb < 4; ++cb) {
            const short8 vfa = *(const short8*)&Vt[(cb * 16 + fn) * 72 + quad * 8];
            o[cb] = __builtin_amdgcn_mfma_f32_16x16x32_bf16(pf0, vfa, o[cb], 0, 0, 0);
        }
        #pragma unroll
        for (int cb = 0; cb < 4; ++cb) {
            const short8 vfb = *(const short8*)&Vt[(cb * 16 + fn) * 72 + 32 + quad * 8];
            o[cb] = __builtin_amdgcn_mfma_f32_16x16x32_bf16(pf1, vfb, o[cb], 0, 0, 0);
        }
        __builtin_amdgcn_s_setprio(0);
    }

    float li[4];
    #pragma unroll
    for (int rg = 0; rg < 4; ++rg)
        li[rg] = 1.f / fmaxf(Ll[wave][quad * 4 + rg], 1e-20f);
    #pragma unroll
    for (int cb = 0; cb < 4; ++cb)
        #pragma unroll
        for (int rg = 0; rg < 4; ++rg) {
            const size_t row = (size_t)(b * TS + q0 + wave * 16 + quad * 4 + rg);
            Out[row * DM + h * 64 + cb * 16 + fn] = f2b(o[cb][rg] * li[rg]);
        }
}

// ---------------------------------------------------------------------------
__global__ __launch_bounds__(256)
void transW(const float* __restrict__ W, bf16* __restrict__ Wt, int K, int N)
{
    __shared__ float t[32][33];
    const int k0 = blockIdx.x * 32, n0 = blockIdx.y * 32;
    const int tx = threadIdx.x, ty = threadIdx.y;
    #pragma unroll
    for (int i = 0; i < 4; ++i)
        t[ty + i * 8][tx] = W[(size_t)(k0 + ty + i * 8) * N + n0 + tx];
    __syncthreads();
    #pragma unroll
    for (int i = 0; i < 4; ++i)
        Wt[(size_t)(n0 + ty + i * 8) * K + k0 + tx] = f2b(t[tx][ty + i * 8]);
}

__global__ __launch_bounds__(256)
void pack_bias(const float* __restrict__ bq, const float* __restrict__ bk,
               const float* __restrict__ bv, float* __restrict__ out)
{
    const int i = blockIdx.x * 256 + threadIdx.x;
    if (i < 3 * DM)
        out[i] = (i < DM) ? bq[i] : (i < 2 * DM) ? bk[i - DM] : bv[i - 2 * DM];
}

template <typename T1, typename T2, typename TOUT>
__global__ __launch_bounds__(256)
void add_ln(const T1* __restrict__ a, const T2* __restrict__ r, int ldr,
            const float* __restrict__ gamma, const float* __restrict__ beta,
            TOUT* __restrict__ out)
{
    const int row = blockIdx.x;
    const size_t offa = (size_t)row * DM;
    const size_t offr = (size_t)row * ldr;
    const int tid = threadIdx.x;

    float v[3];
    float s = 0.f, s2 = 0.f;
    #pragma unroll
    for (int j = 0; j < 3; ++j) {
        const int i = tid + j * 256;
        const float t = ldf(a + offa + i) + ldf(r + offr + i);
        v[j] = t; s += t; s2 += t * t;
    }
    __shared__ float red[256], red2[256];
    red[tid] = s; red2[tid] = s2;
    __syncthreads();
    #pragma unroll
    for (int st = 128; st > 0; st >>= 1) {
        if (tid < st) { red[tid] += red[tid + st]; red2[tid] += red2[tid + st]; }
        __syncthreads();
    }
    const float mu   = red[0] * (1.f / DM);
    const float var  = red2[0] * (1.f / DM) - mu * mu;
    const float rstd = rsqrtf(var + EPS);
    #pragma unroll
    for (int j = 0; j < 3; ++j) {
        const int i = tid + j * 256;
        stf(out + offa + i, (v[j] - mu) * rstd * gamma[i] + beta[i]);
    }
}

// ---------------------------------------------------------------------------
extern "C" void kernel_launch(void* const* d_in, const int* in_sizes, int n_in,
                              void* d_out, int out_size, void* d_ws, size_t ws_size,
                              hipStream_t stream)
{
    (void)in_sizes; (void)n_in; (void)out_size; (void)ws_size;

    const float* x   = (const float*)d_in[0];
    const float* wq  = (const float*)d_in[1];  const float* bq  = (const float*)d_in[2];
    const float* wk  = (const float*)d_in[3];  const float* bk  = (const float*)d_in[4];
    const float* wv  = (const float*)d_in[5];  const float* bv  = (const float*)d_in[6];
    const float* wo  = (const float*)d_in[7];  const float* bo  = (const float*)d_in[8];
    const float* w1  = (const float*)d_in[9];  const float* b1  = (const float*)d_in[10];
    const float* w2  = (const float*)d_in[11]; const float* b2  = (const float*)d_in[12];
    const float* g1  = (const float*)d_in[13]; const float* be1 = (const float*)d_in[14];
    const float* g2  = (const float*)d_in[15]; const float* be2 = (const float*)d_in[16];

    // ws layout (bf16 elems), ~59.8 MB (proven round 6):
    //   QKVb [8192][2304] = 3S | Hb = S | wbuf = 2*DFF*DM | bqkv fp32[2304]
    const size_t S = (size_t)MTOK * DM;
    bf16* QKVb = (bf16*)d_ws;
    bf16* Hb   = QKVb + 3 * S;
    bf16* wbuf = Hb + S;
    float* bqkv = (float*)(wbuf + (size_t)2 * DFF * DM);
    bf16* F1 = QKVb;              // FFN hidden chunk [4096][3072]
    bf16* Yb = QKVb + 2 * S;      // FFN out
    bf16* Pb = QKVb + DM;         // O-proj out -> K-band (dead), ld 2304
    bf16* Ao = Hb;                // attention out (dense; Hb free until LN1)
    bf16* xb = Hb;                // x as bf16 (dead after QKV proj; Hb free)

    const dim3 tblk(32, 8);
    const dim3 blk(256);

    // x -> bf16 (enables global_load_lds staging in the QKV GEMM)
    xcvt<<<dim3(3072), blk, 0, stream>>>(x, xb);

    // QKV projection
    transW<<<dim3(24, 24), tblk, 0, stream>>>(wq, wbuf,                    DM, DM);
    transW<<<dim3(24, 24), tblk, 0, stream>>>(wk, wbuf + (size_t)DM * DM,  DM, DM);
    transW<<<dim3(24, 24), tblk, 0, stream>>>(wv, wbuf + (size_t)2*DM*DM,  DM, DM);
    pack_bias<<<dim3(9), blk, 0, stream>>>(bq, bk, bv, bqkv);
    gemm_lds<0><<<dim3(18, 64), blk, 0, stream>>>(
        xb, DM, wbuf, bqkv, QKVb, 3 * DM, 3 * DM, DM);

    // MFMA flash attention -> Ao (dense 768; overwrites dead xb)
    attn_v6<<<dim3(64, NB * NH), blk, 0, stream>>>(QKVb, Ao);

    // O-projection (Ao -> K-band), LN1 -> Hb (overwrites Ao after read)
    transW<<<dim3(24, 24), tblk, 0, stream>>>(wo, wbuf, DM, DM);
    gemm_lds<0><<<dim3(6, 64), blk, 0, stream>>>(
        Ao, DM, wbuf, bo, Pb, 3 * DM, DM, DM);
    add_ln<float, bf16, bf16><<<dim3(MTOK), blk, 0, stream>>>(
        x, Pb, 3 * DM, g1, be1, Hb);

    // FFN (chunked over M; F1/Yb live in the dead QKVb region)
    transW<<<dim3(24, 96), tblk, 0, stream>>>(w1, wbuf, DM, DFF);
    bf16* w2t = wbuf + (size_t)DFF * DM;
    transW<<<dim3(96, 24), tblk, 0, stream>>>(w2, w2t, DFF, DM);
    for (int m0 = 0; m0 < MTOK; m0 += 4096) {
        gemm_lds<1><<<dim3(24, 32), blk, 0, stream>>>(
            Hb + (size_t)m0 * DM, DM, wbuf, b1, F1, DFF, DFF, DM);
        gemm_lds<0><<<dim3(6, 32), blk, 0, stream>>>(
            F1, DFF, w2t, b2, Yb + (size_t)m0 * DM, DM, DM, DFF);
    }

    add_ln<bf16, bf16, float><<<dim3(MTOK), blk, 0, stream>>>(
        Hb, Yb, DM, g2, be2, (float*)d_out);
}